// Round 4
// baseline (667.426 us; speedup 1.0000x reference)
//
#include <hip/hip_runtime.h>

#define BB 1024
#define NN 128
#define VV 200
#define HH 400
#define GRID 1024

struct KParams {
  const float *merged, *x, *a;
  const float *Wq_aug,*bq_aug,*Wk_aug,*bk_aug,*Wv_aug,*bv_aug;
  const float *Wq_o,*bq_o,*Wk_o,*bk_o,*Wv_o,*bv_o;
  const float *bn_g,*bn_b,*W3,*b3,*W4,*b4,*W0,*b0,*W1,*b1,*W2,*b2;
  float *out;
  float *t_buf,*mean_b,*rstd_b,*mlp_part,*headv_ws,*h1_buf;
  unsigned *bar;
};

__device__ inline float wave_sum(float v){
  for (int o=32;o>0;o>>=1) v += __shfl_down(v,o);
  return v;
}
__device__ inline float wave_max(float v){
  for (int o=32;o>0;o>>=1) v = fmaxf(v, __shfl_down(v,o));
  return v;
}

// Grid barrier: safe because grid == co-resident capacity (see launch_bounds
// note below). Counter zeroed by hipMemsetAsync before each launch.
__device__ inline void grid_barrier(unsigned* cnt, int tid){
  __syncthreads();
  if (tid==0){
    __threadfence();                          // release this block's writes
    atomicAdd(cnt, 1u);
    while (__hip_atomic_load(cnt, __ATOMIC_ACQUIRE, __HIP_MEMORY_SCOPE_AGENT)
           < (unsigned)GRID)
      __builtin_amdgcn_s_sleep(2);
  }
  __syncthreads();
  __threadfence();                            // acquire for all threads
}

// __launch_bounds__(256,4): 4 waves/EU minimum -> VGPR<=128 -> every CU fits
// >=4 blocks (LDS ~24.6KB -> 6 blocks by LDS). grid=1024 = 4*256CU, so all
// blocks co-resident; manual barrier is deadlock-free.
__global__ __launch_bounds__(256, 4) void mega(KParams p)
{
  const int bid = blockIdx.x;
  const int tid = threadIdx.x;
  const int wv = tid>>6, lane = tid&63;

  // ---- shared memory (phases reuse disjoint arrays; total ~24.6 KB) ----
  __shared__ float q_aug[VV], q_o[VV];
  __shared__ float wkq_aug[14], wkq_o[7];
  __shared__ float qbk_aug_s, qbk_o_s;
  __shared__ float kv[NN*14];
  __shared__ float s_aug[NN], s_o[NN];
  __shared__ float wgt[3][NN];
  __shared__ unsigned char msk[3][NN];
  __shared__ float wf[3][14];
  __shared__ int anyf[3];
  __shared__ int w0cnt;
  __shared__ float ls[4][4], ls2[4][4];
  __shared__ float tn[4][VV];          // heads: 4 batches x 200 (16B-aligned rows)
  __shared__ float redh[4][4];
  __shared__ float part[4][64][9];     // mlp partials (pad 9)

  // ================= Phase 1: attention + ego-MLP layer 0 (b = bid) =========
  {
    const int b = bid;
    const float* base = p.merged + (size_t)b*NN*15;
    float sub_bus = base[0];
    float sub_loc = base[2];

    // ego-MLP layer 0
    {
      const float* xb = p.x + (size_t)b*NN*8;
      float e0 = xb[4], e1 = xb[5], e2 = xb[6], e3 = p.a[b];
      for (int i=tid;i<HH;i+=256){
        float v = p.b0[i] + e0*p.W0[0*HH+i] + e1*p.W0[1*HH+i]
                          + e2*p.W0[2*HH+i] + e3*p.W0[3*HH+i];
        p.h1_buf[(size_t)b*HH+i] = fmaxf(v, 0.0f);
      }
    }

    if (tid < VV) {
      float qa = p.bq_aug[tid], qo = p.bq_o[tid];
      for (int j=1;j<7;j++){
        float e = base[j];
        qa += e * p.Wq_aug[j*VV+tid];
        qo += e * p.Wq_o[j*VV+tid];
      }
      q_aug[tid]=qa; q_o[tid]=qo;
    }
    __syncthreads();

    for (int r=wv; r<23; r+=4){
      const float* coef; const float* qv;
      if (r<14)      { coef = p.Wk_aug + r*VV;      qv = q_aug; }
      else if (r==14){ coef = p.bk_aug;             qv = q_aug; }
      else if (r<22) { coef = p.Wk_o + (r-15)*VV;   qv = q_o;   }
      else           { coef = p.bk_o;               qv = q_o;   }
      float pr=0;
      for (int d=lane; d<VV; d+=64) pr += coef[d]*qv[d];
      pr = wave_sum(pr);
      if (lane==0){
        if (r<14) wkq_aug[r]=pr;
        else if (r==14) qbk_aug_s=pr;
        else if (r<22) wkq_o[r-15]=pr;
        else qbk_o_s=pr;
      }
    }
    __syncthreads();

    const float scale = 0.07071067811865475f; // 1/sqrt(200)
    bool f0=false;
    int prior = 0;
    if (tid < NN){
      float m[15];
      for (int i=0;i<15;i++) m[i] = base[tid*15+i];
      m[0]-=sub_bus; m[7]-=sub_bus;
      for (int f=0;f<14;f++) kv[tid*14+f]=m[f];
      float flag=m[14], loc=m[2];
      f0 = (flag==0.0f);
      bool um = (loc<sub_loc) && (flag==1.0f);
      bool dm = (loc>sub_loc) && (flag==1.0f);
      float sa = qbk_aug_s, so = qbk_o_s;
      for (int f=0;f<14;f++) sa += m[f]*wkq_aug[f];
      for (int f=0;f<7;f++)  so += m[f]*wkq_o[f];
      s_aug[tid]=sa*scale; s_o[tid]=so*scale;
      msk[0][tid]=um; msk[1][tid]=dm;
      unsigned long long bal = __ballot(f0);
      prior = __popcll(bal & ((1ull<<lane)-1ull));
      if (tid==0) w0cnt = __popcll(bal);
    }
    __syncthreads();
    if (tid < NN){
      int ptot = prior + (wv==1 ? w0cnt : 0);
      msk[2][tid] = (unsigned char)(f0 && (ptot>0));
    }
    __syncthreads();

    if (wv < 3){
      const float* sarr = (wv==2)? s_o : s_aug;
      float mx=-3e38f;
      for (int i=lane;i<NN;i+=64) if (msk[wv][i]) mx = fmaxf(mx, sarr[i]);
      mx = wave_max(mx);
      mx = __shfl(mx, 0);
      float sum=0;
      for (int i=lane;i<NN;i+=64) if (msk[wv][i]) sum += expf(sarr[i]-mx);
      sum = wave_sum(sum);
      sum = __shfl(sum, 0);
      int any = (mx > -1e38f) ? 1 : 0;
      float inv = any ? 1.0f/sum : 0.0f;
      for (int i=lane;i<NN;i+=64)
        wgt[wv][i] = msk[wv][i] ? expf(sarr[i]-mx)*inv : 0.0f;
      if (lane==0) anyf[wv]=any;
    }
    __syncthreads();

    for (int r=wv; r<35; r+=4){
      int mi, f;
      if (r<14){mi=0;f=r;} else if (r<28){mi=1;f=r-14;} else {mi=2;f=r-28;}
      float pr=0;
      for (int n=lane;n<NN;n+=64) pr += wgt[mi][n]*kv[n*14+f];
      pr=wave_sum(pr);
      if (lane==0) wf[mi][f]=pr;
    }
    __syncthreads();

    if (tid < VV){
      float uv=p.bv_aug[tid], dv=p.bv_aug[tid], ov=p.bv_o[tid];
      for (int f=0;f<14;f++){
        float w = p.Wv_aug[f*VV+tid];
        uv += wf[0][f]*w;
        dv += wf[1][f]*w;
      }
      for (int f=0;f<7;f++) ov += wf[2][f]*p.Wv_o[f*VV+tid];
      if (!anyf[0]) uv=0.0f;
      if (!anyf[1]) dv=0.0f;
      if (!anyf[2]) ov=0.0f;
      float* tb = p.t_buf + (size_t)b*600;
      tb[tid]=uv; tb[200+tid]=dv; tb[400+tid]=ov;
    }
  }

  grid_barrier(p.bar+0, tid);

  // ================= Phase 2: BN stats (blocks 0..149, 4 channels each) =====
  if (bid < 150){
    int c0 = bid*4;
    float s[4]={0,0,0,0}, s2[4]={0,0,0,0};
    for (int b=tid;b<BB;b+=256){
      float4 v = *reinterpret_cast<const float4*>(p.t_buf + (size_t)b*600 + c0);
      s[0]+=v.x; s[1]+=v.y; s[2]+=v.z; s[3]+=v.w;
      s2[0]+=v.x*v.x; s2[1]+=v.y*v.y; s2[2]+=v.z*v.z; s2[3]+=v.w*v.w;
    }
    for (int c=0;c<4;c++){ s[c]=wave_sum(s[c]); s2[c]=wave_sum(s2[c]); }
    if (lane==0){
      for (int c=0;c<4;c++){ ls[wv][c]=s[c]; ls2[wv][c]=s2[c]; }
    }
    __syncthreads();
    if (tid<4){
      float S =ls[0][tid]+ls[1][tid]+ls[2][tid]+ls[3][tid];
      float S2=ls2[0][tid]+ls2[1][tid]+ls2[2][tid]+ls2[3][tid];
      float mean = S*(1.0f/BB);
      float var  = S2*(1.0f/BB) - mean*mean;
      p.mean_b[c0+tid]=mean;
      p.rstd_b[c0+tid]=rsqrtf(var+1e-5f);
    }
  }

  grid_barrier(p.bar+1, tid);

  // ================= Phase 3: heads (1536 units) + mlp (896 units) ==========
  for (unsigned u=bid; u<2432u; u+=GRID){
    if (u < 1536u){
      // heads unit: 4 batches x 1 head
      int k  = u >> 8;          // 0..5
      int xg = u & 255;         // 0..255
      int bb = xg*4;
      int t3 = k>>1;
      __syncthreads();          // protect tn/redh reuse across units
      for (int idx=tid; idx<800; idx+=256){
        int bl=idx/200, v=idx-bl*200;
        int c = t3*200+v;
        tn[bl][v] = p.bn_g[v]*(p.t_buf[(size_t)(bb+bl)*600+c]-p.mean_b[c])
                    *p.rstd_b[c] + p.bn_b[v];
      }
      __syncthreads();
      int g = tid;
      int gc = (g<200) ? g : 199;
      float acc0,acc1,acc2,acc3;
      {
        float bias = p.b3[k*200+gc];
        acc0=acc1=acc2=acc3=bias;
      }
      const float* w3p = p.W3 + (size_t)k*40000 + gc;
      const float4* tn4 = reinterpret_cast<const float4*>(&tn[0][0]); // [4][50]
      #pragma unroll 2
      for (int v4=0; v4<50; v4++){
        int v = v4*4;
        float w0 = w3p[(size_t)v*200];
        float w1 = w3p[(size_t)(v+1)*200];
        float w2 = w3p[(size_t)(v+2)*200];
        float w3v= w3p[(size_t)(v+3)*200];
        float4 t0 = tn4[0*50+v4];
        float4 t1 = tn4[1*50+v4];
        float4 t2 = tn4[2*50+v4];
        float4 t3v= tn4[3*50+v4];
        acc0 += t0.x*w0 + t0.y*w1 + t0.z*w2 + t0.w*w3v;
        acc1 += t1.x*w0 + t1.y*w1 + t1.z*w2 + t1.w*w3v;
        acc2 += t2.x*w0 + t2.y*w1 + t2.z*w2 + t2.w*w3v;
        acc3 += t3v.x*w0 + t3v.y*w1 + t3v.z*w2 + t3v.w*w3v;
      }
      float w4 = p.W4[k*200+gc];
      float c0 = (acc0>0.f?acc0:(expf(acc0)-1.0f))*w4;
      float c1 = (acc1>0.f?acc1:(expf(acc1)-1.0f))*w4;
      float c2 = (acc2>0.f?acc2:(expf(acc2)-1.0f))*w4;
      float c3 = (acc3>0.f?acc3:(expf(acc3)-1.0f))*w4;
      if (g>=200){ c0=c1=c2=c3=0.0f; }
      c0 = wave_sum(c0); c1 = wave_sum(c1);
      c2 = wave_sum(c2); c3 = wave_sum(c3);
      if (lane==0){ redh[wv][0]=c0; redh[wv][1]=c1; redh[wv][2]=c2; redh[wv][3]=c3; }
      __syncthreads();
      if (tid<4){
        float ssum = redh[0][tid]+redh[1][tid]+redh[2][tid]+redh[3][tid];
        p.headv_ws[(size_t)(bb+tid)*6 + k] = ssum + p.b4[k];
      }
    } else {
      // mlp unit: 8 batches x 64-wide j-tile
      unsigned mu = u - 1536u;
      int js = mu >> 7;         // 0..6
      int xg = mu & 127;
      int bb = xg*8;
      int jl = tid & 63;
      int ic = tid >> 6;
      int j  = js*64 + jl;
      bool jok = (j < HH);
      int jc = jok ? j : (HH-1);
      float acc[8]={0,0,0,0,0,0,0,0};
      {
        const float* w1p = p.W1 + jc;
        const float* h0 = p.h1_buf + (size_t)(bb+0)*HH;
        const float* h1 = p.h1_buf + (size_t)(bb+1)*HH;
        const float* h2 = p.h1_buf + (size_t)(bb+2)*HH;
        const float* h3 = p.h1_buf + (size_t)(bb+3)*HH;
        const float* h4 = p.h1_buf + (size_t)(bb+4)*HH;
        const float* h5 = p.h1_buf + (size_t)(bb+5)*HH;
        const float* h6 = p.h1_buf + (size_t)(bb+6)*HH;
        const float* h7 = p.h1_buf + (size_t)(bb+7)*HH;
        int i0 = ic*100;
        #pragma unroll 4
        for (int i=i0;i<i0+100;i++){
          float w = w1p[(size_t)i*HH];
          acc[0]+=h0[i]*w; acc[1]+=h1[i]*w; acc[2]+=h2[i]*w; acc[3]+=h3[i]*w;
          acc[4]+=h4[i]*w; acc[5]+=h5[i]*w; acc[6]+=h6[i]*w; acc[7]+=h7[i]*w;
        }
      }
      __syncthreads();          // protect part reuse across units
      for (int bl=0;bl<8;bl++) part[ic][jl][bl]=acc[bl];
      __syncthreads();
      if (tid < 64){
        float bj = p.b1[jc], w2 = p.W2[jc];
        for (int bl=0;bl<8;bl++){
          float s = part[0][jl][bl]+part[1][jl][bl]
                  + part[2][jl][bl]+part[3][jl][bl];
          s += bj;
          float contrib = jok ? fmaxf(s, 0.0f)*w2 : 0.0f;
          float tot = wave_sum(contrib);
          if (jl==0) p.mlp_part[(size_t)(bb+bl)*8 + js] = tot;
        }
      }
    }
  }

  grid_barrier(p.bar+2, tid);

  // ================= Phase 4: finalize (blocks 0..3) ========================
  if (bid < 4){
    int b = bid*256 + tid;
    const float* mp = p.mlp_part + (size_t)b*8;
    float q = mp[0]+mp[1]+mp[2]+mp[3]+mp[4]+mp[5]+mp[6] + p.b2[0];
    const float* hv = p.headv_ws + (size_t)b*6;
    float A1 = hv[0]+hv[2]+hv[4];
    float A2 = hv[1]+hv[3]+hv[5];
    p.out[b]      = q;
    p.out[BB+b]   = A2;
    p.out[2*BB+b] = q+A1;
    p.out[3*BB+b] = q+A2;
    if (b==0) p.out[4*BB]=0.0f;
  }
}

extern "C" void kernel_launch(void* const* d_in, const int* in_sizes, int n_in,
                              void* d_out, int out_size, void* d_ws, size_t ws_size,
                              hipStream_t stream)
{
  (void)in_sizes; (void)n_in; (void)out_size; (void)ws_size;
  float* ws  = (float*)d_ws;

  KParams P;
  P.merged=(const float*)d_in[0];
  P.x     =(const float*)d_in[1];
  P.a     =(const float*)d_in[2];
  P.Wq_aug=(const float*)d_in[3];  P.bq_aug=(const float*)d_in[4];
  P.Wk_aug=(const float*)d_in[5];  P.bk_aug=(const float*)d_in[6];
  P.Wv_aug=(const float*)d_in[7];  P.bv_aug=(const float*)d_in[8];
  P.Wq_o  =(const float*)d_in[9];  P.bq_o  =(const float*)d_in[10];
  P.Wk_o  =(const float*)d_in[11]; P.bk_o  =(const float*)d_in[12];
  P.Wv_o  =(const float*)d_in[13]; P.bv_o  =(const float*)d_in[14];
  P.bn_g  =(const float*)d_in[15]; P.bn_b  =(const float*)d_in[16];
  P.W3    =(const float*)d_in[17]; P.b3    =(const float*)d_in[18];
  P.W4    =(const float*)d_in[19]; P.b4    =(const float*)d_in[20];
  P.W0    =(const float*)d_in[21]; P.b0    =(const float*)d_in[22];
  P.W1    =(const float*)d_in[23]; P.b1    =(const float*)d_in[24];
  P.W2    =(const float*)d_in[25]; P.b2    =(const float*)d_in[26];
  P.out   = (float*)d_out;
  P.t_buf   = ws;                  // 1024*600
  P.mean_b  = ws + 614400;         // 600
  P.rstd_b  = ws + 615000;         // 600
  P.mlp_part= ws + 615600;         // 1024*8
  P.headv_ws= ws + 623792;         // 1024*6
  P.h1_buf  = ws + 629936;         // 1024*400
  P.bar     = (unsigned*)(ws + 1039536); // 3 uints

  hipMemsetAsync((void*)P.bar, 0, 3*sizeof(unsigned), stream);
  hipLaunchKernelGGL(mega, dim3(GRID), dim3(256), 0, stream, P);
}

// Round 5
// 60.970 us; speedup vs baseline: 10.9468x; 10.9468x over previous
//
#include <hip/hip_runtime.h>

#define BB 1024
#define NN 128
#define VV 200
#define HH 400

__device__ inline float wave_sum(float v){
  for (int o=32;o>0;o>>=1) v += __shfl_down(v,o);
  return v;
}
__device__ inline float xsum(float v){
  for (int o=1;o<64;o<<=1) v += __shfl_xor(v,o);
  return v;
}
__device__ inline float xmax(float v){
  for (int o=1;o<64;o<<=1) v = fmaxf(v,__shfl_xor(v,o));
  return v;
}

// ---------------- Kernel 0: data-independent score-projection precompute -----
// C_aug=Wq_aug·Wk_aug^T (7x14) etc. 184 dot products of length 200.
__global__ __launch_bounds__(64) void prep_k(
    const float* __restrict__ Wq_aug, const float* __restrict__ bq_aug,
    const float* __restrict__ Wk_aug, const float* __restrict__ bk_aug,
    const float* __restrict__ Wq_o,  const float* __restrict__ bq_o,
    const float* __restrict__ Wk_o,  const float* __restrict__ bk_o,
    float* __restrict__ prep)
{
  int t = blockIdx.x;            // 0..183
  int lane = threadIdx.x;
  const float *A, *Bv;
  if (t<98)      { int i=t/14, f=t-i*14; A=Wq_aug+i*VV; Bv=Wk_aug+f*VV; }
  else if (t<112){ int f=t-98;           A=bq_aug;      Bv=Wk_aug+f*VV; }
  else if (t<119){ int i=t-112;          A=Wq_aug+i*VV; Bv=bk_aug; }
  else if (t==119){                      A=bq_aug;      Bv=bk_aug; }
  else if (t<169){ int r=t-120; int i=r/7, f=r-i*7; A=Wq_o+i*VV; Bv=Wk_o+f*VV; }
  else if (t<176){ int f=t-169;          A=bq_o;        Bv=Wk_o+f*VV; }
  else if (t<183){ int i=t-176;          A=Wq_o+i*VV;   Bv=bk_o; }
  else           {                       A=bq_o;        Bv=bk_o; }
  float s=0;
  for (int d=lane; d<VV; d+=64) s += A[d]*Bv[d];
  s = xsum(s);
  if (lane==0) prep[t]=s;
}

// ---------------- Kernel 1: attention, ONE WAVE PER BATCH, no syncthreads ----
// prep layout: C_aug[i][f]=prep[i*14+f]; d_aug=prep[98+f]; e_aug=prep[112+i];
// f_aug=prep[119]; C_o[i][f]=prep[120+i*7+f]; d_o=prep[169+f];
// e_o=prep[176+i]; f_o=prep[183].
__global__ __launch_bounds__(64) void attn_v2(
    const float* __restrict__ merged, const float* __restrict__ prep,
    const float* __restrict__ Wv_aug, const float* __restrict__ bv_aug,
    const float* __restrict__ Wv_o,  const float* __restrict__ bv_o,
    float* __restrict__ t_buf)
{
  const int b = blockIdx.x;
  const int lane = threadIdx.x;
  const float* base = merged + (size_t)b*NN*15;

  float sub_bus = base[0], sub_loc = base[2];
  float eg[7];
  eg[0]=0.0f;
  for (int i=1;i<7;i++) eg[i]=base[i];

  // wkq / qbk from precomputed C (ego7[0]==0 -> skip i=0)
  float wkqa[14], wkqo[7];
  #pragma unroll
  for (int f=0;f<14;f++){
    float s = prep[98+f];
    for (int i=1;i<7;i++) s += eg[i]*prep[i*14+f];
    wkqa[f]=s;
  }
  float qbka = prep[119];
  for (int i=1;i<7;i++) qbka += eg[i]*prep[112+i];
  #pragma unroll
  for (int f=0;f<7;f++){
    float s = prep[169+f];
    for (int i=1;i<7;i++) s += eg[i]*prep[120+i*7+f];
    wkqo[f]=s;
  }
  float qbko = prep[183];
  for (int i=1;i<7;i++) qbko += eg[i]*prep[176+i];

  // two rows per lane
  float m0[15], m1[15];
  const float* r0 = base + (size_t)lane*15;
  const float* r1 = base + (size_t)(lane+64)*15;
  #pragma unroll
  for (int i=0;i<15;i++){ m0[i]=r0[i]; m1[i]=r1[i]; }
  m0[0]-=sub_bus; m0[7]-=sub_bus;
  m1[0]-=sub_bus; m1[7]-=sub_bus;

  const float scale = 0.07071067811865475f; // 1/sqrt(200)
  float sa0=qbka, sa1=qbka, so0=qbko, so1=qbko;
  #pragma unroll
  for (int f=0;f<14;f++){ sa0+=m0[f]*wkqa[f]; sa1+=m1[f]*wkqa[f]; }
  #pragma unroll
  for (int f=0;f<7;f++){ so0+=m0[f]*wkqo[f]; so1+=m1[f]*wkqo[f]; }
  sa0*=scale; sa1*=scale; so0*=scale; so1*=scale;

  float fl0=m0[14], fl1=m1[14], lo0=m0[2], lo1=m1[2];
  bool um0=(lo0<sub_loc)&&(fl0==1.0f), um1=(lo1<sub_loc)&&(fl1==1.0f);
  bool dm0=(lo0>sub_loc)&&(fl0==1.0f), dm1=(lo1>sub_loc)&&(fl1==1.0f);
  bool f00=(fl0==0.0f), f01=(fl1==0.0f);
  unsigned long long bal0=__ballot(f00), bal1=__ballot(f01);
  unsigned long long below=(1ull<<lane)-1ull;
  int prior0=__popcll(bal0&below);
  int prior1=__popcll(bal0)+__popcll(bal1&below);
  bool om0=f00&&(prior0>0), om1=f01&&(prior1>0);

  const float NINF=-3.0e38f;
  // softmax u
  float mu_ = xmax(fmaxf(um0?sa0:NINF, um1?sa1:NINF));
  bool anyu = mu_>-1e38f;
  float eu0 = um0?expf(sa0-mu_):0.0f, eu1 = um1?expf(sa1-mu_):0.0f;
  float su = xsum(eu0+eu1);
  float ivu = anyu?1.0f/su:0.0f;
  float wu0=eu0*ivu, wu1=eu1*ivu;
  // softmax d
  float md_ = xmax(fmaxf(dm0?sa0:NINF, dm1?sa1:NINF));
  bool anyd = md_>-1e38f;
  float ed0 = dm0?expf(sa0-md_):0.0f, ed1 = dm1?expf(sa1-md_):0.0f;
  float sd = xsum(ed0+ed1);
  float ivd = anyd?1.0f/sd:0.0f;
  float wd0=ed0*ivd, wd1=ed1*ivd;
  // softmax o
  float mo_ = xmax(fmaxf(om0?so0:NINF, om1?so1:NINF));
  bool anyo = mo_>-1e38f;
  float eo0 = om0?expf(so0-mo_):0.0f, eo1 = om1?expf(so1-mo_):0.0f;
  float so = xsum(eo0+eo1);
  float ivo = anyo?1.0f/so:0.0f;
  float wo0=eo0*ivo, wo1=eo1*ivo;

  // weighted feature sums (35 butterfly reductions, ILP-interleaved)
  float wfu[14], wfd[14], wfo[7];
  #pragma unroll
  for (int f=0;f<14;f++){
    wfu[f]=xsum(wu0*m0[f]+wu1*m1[f]);
    wfd[f]=xsum(wd0*m0[f]+wd1*m1[f]);
  }
  #pragma unroll
  for (int f=0;f<7;f++) wfo[f]=xsum(wo0*m0[f]+wo1*m1[f]);

  // project through Wv to 200 channels
  float* tb = t_buf + (size_t)b*600;
  #pragma unroll
  for (int rep=0;rep<4;rep++){
    int c = lane + rep*64;
    if (c < VV){
      float uv=bv_aug[c], dv=bv_aug[c], ov=bv_o[c];
      #pragma unroll
      for (int f=0;f<14;f++){
        float w=Wv_aug[f*VV+c];
        uv+=wfu[f]*w; dv+=wfd[f]*w;
      }
      #pragma unroll
      for (int f=0;f<7;f++) ov+=wfo[f]*Wv_o[f*VV+c];
      if(!anyu) uv=0.0f;
      if(!anyd) dv=0.0f;
      if(!anyo) ov=0.0f;
      tb[c]=uv; tb[200+c]=dv; tb[400+c]=ov;
    }
  }
}

// ---------------- Kernel 2: BN stats (150 blocks) + ego-MLP (896 blocks) -----
__global__ __launch_bounds__(256) void bn_mlp(
    const float* __restrict__ t_buf,
    float* __restrict__ mean_out, float* __restrict__ rstd_out,
    const float* __restrict__ x, const float* __restrict__ a,
    const float* __restrict__ W0, const float* __restrict__ b0,
    const float* __restrict__ W1, const float* __restrict__ b1,
    const float* __restrict__ W2,
    float* __restrict__ mlp_part)
{
  int tid=threadIdx.x, wv=tid>>6, lane=tid&63;
  __shared__ float smem[8*HH + 4*64*9 + 64];   // mlp: h1s|part|ego ; bn: ls/ls2

  if (blockIdx.x < 150){
    int c0 = blockIdx.x*4;
    float* ls  = smem;        // [4][4]
    float* ls2 = smem+16;     // [4][4]
    float s[4]={0,0,0,0}, s2[4]={0,0,0,0};
    #pragma unroll 2
    for (int b=tid;b<BB;b+=256){
      float4 v = *reinterpret_cast<const float4*>(t_buf + (size_t)b*600 + c0);
      s[0]+=v.x; s[1]+=v.y; s[2]+=v.z; s[3]+=v.w;
      s2[0]+=v.x*v.x; s2[1]+=v.y*v.y; s2[2]+=v.z*v.z; s2[3]+=v.w*v.w;
    }
    for (int c=0;c<4;c++){ s[c]=wave_sum(s[c]); s2[c]=wave_sum(s2[c]); }
    if (lane==0){
      for (int c=0;c<4;c++){ ls[wv*4+c]=s[c]; ls2[wv*4+c]=s2[c]; }
    }
    __syncthreads();
    if (tid<4){
      float S =ls[0*4+tid]+ls[1*4+tid]+ls[2*4+tid]+ls[3*4+tid];
      float S2=ls2[0*4+tid]+ls2[1*4+tid]+ls2[2*4+tid]+ls2[3*4+tid];
      float mean = S*(1.0f/BB);
      float var  = S2*(1.0f/BB) - mean*mean;
      mean_out[c0+tid]=mean;
      rstd_out[c0+tid]=rsqrtf(var+1e-5f);
    }
  } else {
    unsigned mu = blockIdx.x - 150;
    int js = mu >> 7;          // 0..6
    int xg = mu & 127;
    int bb = xg*8;
    float* h1s  = smem;                 // [8][HH]
    float* part = smem + 8*HH;          // [4][64][9]
    float* ego  = smem + 8*HH + 4*64*9; // [8][4]
    if (tid<32){
      int bl=tid>>2, j=tid&3;
      int b=bb+bl;
      ego[bl*4+j] = (j<3) ? x[(size_t)b*NN*8 + 4 + j] : a[b];
    }
    __syncthreads();
    for (int idx=tid; idx<8*HH; idx+=256){
      int bl = idx/HH, i = idx - bl*HH;
      float v = b0[i] + ego[bl*4+0]*W0[i]      + ego[bl*4+1]*W0[HH+i]
                      + ego[bl*4+2]*W0[2*HH+i] + ego[bl*4+3]*W0[3*HH+i];
      h1s[bl*HH+i] = fmaxf(v,0.0f);
    }
    __syncthreads();
    int jl = tid & 63;
    int ic = tid >> 6;
    int j  = js*64 + jl;
    bool jok = (j < HH);
    int jc = jok ? j : (HH-1);
    float acc[8]={0,0,0,0,0,0,0,0};
    {
      const float* w1p = W1 + jc;
      int i0 = ic*100;
      #pragma unroll 4
      for (int i=i0;i<i0+100;i++){
        float w = w1p[(size_t)i*HH];
        acc[0]+=h1s[0*HH+i]*w; acc[1]+=h1s[1*HH+i]*w;
        acc[2]+=h1s[2*HH+i]*w; acc[3]+=h1s[3*HH+i]*w;
        acc[4]+=h1s[4*HH+i]*w; acc[5]+=h1s[5*HH+i]*w;
        acc[6]+=h1s[6*HH+i]*w; acc[7]+=h1s[7*HH+i]*w;
      }
    }
    for (int bl=0;bl<8;bl++) part[(ic*64+jl)*9+bl]=acc[bl];
    __syncthreads();
    if (tid < 64){
      float bj = b1[jc], w2 = W2[jc];
      for (int bl=0;bl<8;bl++){
        float s = part[(0*64+jl)*9+bl]+part[(1*64+jl)*9+bl]
                + part[(2*64+jl)*9+bl]+part[(3*64+jl)*9+bl];
        s += bj;
        float contrib = jok ? fmaxf(s,0.0f)*w2 : 0.0f;
        float tot = wave_sum(contrib);
        if (jl==0) mlp_part[(size_t)(bb+bl)*8 + js] = tot;
      }
    }
  }
}

// ---------------- Kernel 3: BN apply + one head per block (8 b, 1 k) ---------
__global__ __launch_bounds__(256) void heads_k(
    const float* __restrict__ t_buf, const float* __restrict__ mean_in,
    const float* __restrict__ rstd_in,
    const float* __restrict__ bn_g, const float* __restrict__ bn_b,
    const float* __restrict__ W3, const float* __restrict__ b3,
    const float* __restrict__ W4, const float* __restrict__ b4,
    float* __restrict__ headv_ws)
{
  int bb = blockIdx.x*8;          // 128 groups of 8 b
  int k  = blockIdx.y;            // 0..5
  int tid=threadIdx.x, wv=tid>>6, lane=tid&63;
  int t3 = k>>1;
  __shared__ float tn[8][200];
  for (int idx=tid; idx<1600; idx+=256){
    int bl=idx/200, v=idx-bl*200;
    int c = t3*200+v;
    tn[bl][v] = bn_g[v]*(t_buf[(size_t)(bb+bl)*600+c]-mean_in[c])*rstd_in[c]+bn_b[v];
  }
  __syncthreads();
  float contrib[8]={0,0,0,0,0,0,0,0};
  int g = tid;
  if (g < 200){
    float acc[8];
    float bias = b3[k*200+g];
    for (int bl=0;bl<8;bl++) acc[bl]=bias;
    const float* w3p = W3 + (size_t)k*40000 + g;
    #pragma unroll 4
    for (int v=0;v<200;v++){
      float w = w3p[(size_t)v*200];
      acc[0]+=tn[0][v]*w; acc[1]+=tn[1][v]*w;
      acc[2]+=tn[2][v]*w; acc[3]+=tn[3][v]*w;
      acc[4]+=tn[4][v]*w; acc[5]+=tn[5][v]*w;
      acc[6]+=tn[6][v]*w; acc[7]+=tn[7][v]*w;
    }
    float w4 = W4[k*200+g];
    for (int bl=0;bl<8;bl++){
      float h = acc[bl]>0.f ? acc[bl] : (expf(acc[bl])-1.0f);
      contrib[bl] = h*w4;
    }
  }
  for (int bl=0;bl<8;bl++) contrib[bl]=wave_sum(contrib[bl]);
  __shared__ float red[4][8];
  if (lane==0) for (int bl=0;bl<8;bl++) red[wv][bl]=contrib[bl];
  __syncthreads();
  if (tid<8){
    float s = red[0][tid]+red[1][tid]+red[2][tid]+red[3][tid];
    headv_ws[(size_t)(bb+tid)*6 + k] = s + b4[k];
  }
}

// ---------------- Kernel 4: finalize outputs ---------------------------------
__global__ __launch_bounds__(256) void finalize(
    const float* __restrict__ mlp_part, const float* __restrict__ headv_ws,
    const float* __restrict__ b2, float* __restrict__ out)
{
  int b = blockIdx.x*256 + threadIdx.x;   // grid 4
  if (b < BB){
    const float* mp = mlp_part + (size_t)b*8;
    float q = mp[0]+mp[1]+mp[2]+mp[3]+mp[4]+mp[5]+mp[6] + b2[0];
    const float* hv = headv_ws + (size_t)b*6;
    float A1 = hv[0]+hv[2]+hv[4];
    float A2 = hv[1]+hv[3]+hv[5];
    out[b]      = q;
    out[BB+b]   = A2;
    out[2*BB+b] = q+A1;
    out[3*BB+b] = q+A2;
    if (b==0) out[4*BB]=0.0f;
  }
}

extern "C" void kernel_launch(void* const* d_in, const int* in_sizes, int n_in,
                              void* d_out, int out_size, void* d_ws, size_t ws_size,
                              hipStream_t stream)
{
  (void)in_sizes; (void)n_in; (void)out_size; (void)ws_size;
  const float* merged=(const float*)d_in[0];
  const float* x     =(const float*)d_in[1];
  const float* a     =(const float*)d_in[2];
  const float* Wq_aug=(const float*)d_in[3];  const float* bq_aug=(const float*)d_in[4];
  const float* Wk_aug=(const float*)d_in[5];  const float* bk_aug=(const float*)d_in[6];
  const float* Wv_aug=(const float*)d_in[7];  const float* bv_aug=(const float*)d_in[8];
  const float* Wq_o  =(const float*)d_in[9];  const float* bq_o  =(const float*)d_in[10];
  const float* Wk_o  =(const float*)d_in[11]; const float* bk_o  =(const float*)d_in[12];
  const float* Wv_o  =(const float*)d_in[13]; const float* bv_o  =(const float*)d_in[14];
  const float* bn_g  =(const float*)d_in[15]; const float* bn_b  =(const float*)d_in[16];
  const float* W3    =(const float*)d_in[17]; const float* b3    =(const float*)d_in[18];
  const float* W4    =(const float*)d_in[19]; const float* b4    =(const float*)d_in[20];
  const float* W0    =(const float*)d_in[21]; const float* b0    =(const float*)d_in[22];
  const float* W1    =(const float*)d_in[23]; const float* b1    =(const float*)d_in[24];
  const float* W2    =(const float*)d_in[25]; const float* b2    =(const float*)d_in[26];

  float* out = (float*)d_out;
  float* ws  = (float*)d_ws;
  float* t_buf   = ws;             // 1024*600
  float* mean_b  = ws + 614400;    // 600
  float* rstd_b  = ws + 615000;    // 600
  float* mlp_part= ws + 615600;    // 1024*8
  float* headv_ws= ws + 623792;    // 1024*6
  float* prep_b  = ws + 629936;    // 184

  hipLaunchKernelGGL(prep_k, dim3(184), dim3(64), 0, stream,
      Wq_aug,bq_aug,Wk_aug,bk_aug, Wq_o,bq_o,Wk_o,bk_o, prep_b);
  hipLaunchKernelGGL(attn_v2, dim3(BB), dim3(64), 0, stream,
      merged, prep_b, Wv_aug, bv_aug, Wv_o, bv_o, t_buf);
  hipLaunchKernelGGL(bn_mlp, dim3(150+896), dim3(256), 0, stream,
      t_buf, mean_b, rstd_b, x, a, W0, b0, W1, b1, W2, mlp_part);
  hipLaunchKernelGGL(heads_k, dim3(BB/8,6), dim3(256), 0, stream,
      t_buf, mean_b, rstd_b, bn_g, bn_b, W3, b3, W4, b4, headv_ws);
  hipLaunchKernelGGL(finalize, dim3(4), dim3(256), 0, stream,
      mlp_part, headv_ws, b2, out);
}